// Round 3
// baseline (4816.144 us; speedup 1.0000x reference)
//
#include <hip/hip_runtime.h>
#include <hip/hip_bf16.h>

#define N_NODES 100000
#define N_EDGES 625000
#define D 128
#define N_LAYERS 10
#define SCAN_BLOCKS 98   // ceil(100000/1024)
#define NT 32            // dst nodes per agg block (100000 % 32 == 0 -> 3125 blocks)

typedef __attribute__((ext_vector_type(8))) short bf16x8;
typedef __attribute__((ext_vector_type(4))) float floatx4;

static __device__ __forceinline__ ushort f2bf(float f) {
    uint u = __float_as_uint(f);
    u += 0x7fff + ((u >> 16) & 1);   // round-to-nearest-even
    return (ushort)(u >> 16);
}
static __device__ __forceinline__ float bf2f(ushort h) {
    return __uint_as_float(((uint)h) << 16);
}

// ---------------- CSR build (once per call) ----------------

__global__ void hist_kernel(const int* __restrict__ dst, int* __restrict__ deg) {
    int e = blockIdx.x * blockDim.x + threadIdx.x;
    if (e < N_EDGES) atomicAdd(&deg[dst[e]], 1);
}

__global__ void scanA_kernel(const int* __restrict__ deg, int* __restrict__ offsets,
                             int* __restrict__ blockSums) {
    __shared__ int s[1024];
    int tid = threadIdx.x;
    int i = blockIdx.x * 1024 + tid;
    int v = (i < N_NODES) ? deg[i] : 0;
    s[tid] = v;
    __syncthreads();
    for (int d = 1; d < 1024; d <<= 1) {
        int t = (tid >= d) ? s[tid - d] : 0;
        __syncthreads();
        s[tid] += t;
        __syncthreads();
    }
    if (i < N_NODES) offsets[i] = s[tid] - v;   // exclusive
    if (tid == 1023) blockSums[blockIdx.x] = s[1023];
}

__global__ void scanB_kernel(const int* __restrict__ blockSums, int* __restrict__ blockOffsets) {
    __shared__ int s[128];
    int tid = threadIdx.x;
    int v = (tid < SCAN_BLOCKS) ? blockSums[tid] : 0;
    s[tid] = v;
    __syncthreads();
    for (int d = 1; d < 128; d <<= 1) {
        int t = (tid >= d) ? s[tid - d] : 0;
        __syncthreads();
        s[tid] += t;
        __syncthreads();
    }
    blockOffsets[tid] = s[tid] - v;             // exclusive
}

__global__ void scanC_kernel(int* __restrict__ offsets, const int* __restrict__ blockOffsets) {
    int i = blockIdx.x * 1024 + threadIdx.x;
    if (i < N_NODES) offsets[i] += blockOffsets[blockIdx.x];
}

__global__ void invdeg_kernel(const int* __restrict__ deg, float* __restrict__ invdeg) {
    int i = blockIdx.x * blockDim.x + threadIdx.x;
    if (i < N_NODES) {
        int d = deg[i];
        invdeg[i] = 1.0f / (float)(d > 0 ? d : 1);
    }
}

__global__ void scatter_kernel(const int* __restrict__ src, const int* __restrict__ dst,
                               const int* __restrict__ offsets, int* __restrict__ fill,
                               int2* __restrict__ edges) {
    int e = blockIdx.x * blockDim.x + threadIdx.x;
    if (e < N_EDGES) {
        int d_ = dst[e];
        int pos = offsets[d_] + atomicAdd(&fill[d_], 1);
        int2 p; p.x = src[e]; p.y = d_;
        edges[pos] = p;
    }
}

// ---------------- W hi/lo split into B-fragment layout (once per call) ----------------
// layout: (((layer*4 + s)*16 + ntile)*64 + lane)*8, element j: k = s*32+(lane>>4)*8+j,
// n = ntile*16 + (lane&15); n<128 -> Wl, else Wr (col n-128)
__global__ void wsplit_kernel(const float* __restrict__ Wl, const float* __restrict__ Wr,
                              ushort* __restrict__ Whi, ushort* __restrict__ Wlo) {
    int t = blockIdx.x * blockDim.x + threadIdx.x;
    if (t >= N_LAYERS * 4 * 16 * 64) return;
    int lane  = t & 63;
    int ntile = (t >> 6) & 15;
    int s     = (t >> 10) & 3;
    int layer = t >> 12;
    int n = ntile * 16 + (lane & 15);
    int kbase = s * 32 + (lane >> 4) * 8;
    const float* W = (n < 128) ? (Wl + (size_t)layer * D * D + n)
                               : (Wr + (size_t)layer * D * D + (n - 128));
    size_t off = (size_t)t * 8;
#pragma unroll
    for (int j = 0; j < 8; ++j) {
        float w = W[(size_t)(kbase + j) * D];
        ushort hh = f2bf(w);
        Whi[off + j] = hh;
        Wlo[off + j] = f2bf(w - bf2f(hh));
    }
}

// ---------------- per layer: h = x@Wl (bf16 col-pair packed), z = x@Wr + b (fp32) -------
// block 256 = 4 waves; M-tile 16 rows, K=128.
// waves 0,1 own ntiles {0,1,4,5}/{2,3,6,7} so each lane holds cols (c, c+64) pairs and
// writes h packed: uint j of a row = bf16(col j) | bf16(col j+64) << 16.
// waves 2,3 own ntiles 8..15 -> z (fp32 + bias), in-place-safe over x.
__global__ __launch_bounds__(256) void gemm_hz(
        const float* __restrict__ X, const ushort* __restrict__ Whi,
        const ushort* __restrict__ Wlo, const float* __restrict__ bias,
        uint* __restrict__ h2out, float* __restrict__ z) {
    __shared__ ushort Ahi[4 * 64 * 8];   // [s][lane ^ (s<<2)][8]  (4 KB)
    __shared__ ushort Alo[4 * 64 * 8];

    int tid  = threadIdx.x;
    int lane = tid & 63;
    int wave = tid >> 6;

    // staging indices: thread (r, t0) loads A[row0+r][t0*8 .. t0*8+7]
    int r    = tid >> 4;       // 0..15
    int t0   = tid & 15;       // 0..15 (8-float chunk)
    int s_st = t0 >> 2;
    int q_st = t0 & 3;
    int lanep = (q_st << 4) | r;
    int stIdx = (s_st * 64 + (lanep ^ (s_st << 2))) * 8;

    int q  = lane >> 4;        // D-frag quad
    int cc = lane & 15;        // D-frag col-in-tile

    int ntileMap[4];
#pragma unroll
    for (int nt = 0; nt < 4; ++nt)
        ntileMap[nt] = (wave < 2) ? (wave * 2 + (nt & 1) + ((nt >> 1) << 2))
                                  : (wave * 4 + nt);

    float bsc[4] = {0.f, 0.f, 0.f, 0.f};
    if (wave >= 2) {
#pragma unroll
        for (int nt = 0; nt < 4; ++nt)
            bsc[nt] = bias[((wave * 4 + nt) - 8) * 16 + cc];
    }

    for (int mt = blockIdx.x; mt < N_NODES / 16; mt += gridDim.x) {
        int row0 = mt * 16;
        // ---- stage A tile, split hi/lo ----
        const float* xp = X + (size_t)(row0 + r) * D + t0 * 8;
        float4 v0 = *(const float4*)xp;
        float4 v1 = *(const float4*)(xp + 4);
        float a[8] = {v0.x, v0.y, v0.z, v0.w, v1.x, v1.y, v1.z, v1.w};
        ushort hi8[8], lo8[8];
#pragma unroll
        for (int j = 0; j < 8; ++j) {
            ushort hh = f2bf(a[j]);
            hi8[j] = hh;
            lo8[j] = f2bf(a[j] - bf2f(hh));
        }
        *(bf16x8*)&Ahi[stIdx] = *(bf16x8*)hi8;
        *(bf16x8*)&Alo[stIdx] = *(bf16x8*)lo8;
        __syncthreads();

        // ---- MFMA: 3-pass hi/lo split ----
        floatx4 acc[4];
#pragma unroll
        for (int nt = 0; nt < 4; ++nt) acc[nt] = (floatx4){0.f, 0.f, 0.f, 0.f};
#pragma unroll
        for (int s = 0; s < 4; ++s) {
            int aIdx = (s * 64 + (lane ^ (s << 2))) * 8;
            bf16x8 ah = *(const bf16x8*)&Ahi[aIdx];
            bf16x8 al = *(const bf16x8*)&Alo[aIdx];
#pragma unroll
            for (int nt = 0; nt < 4; ++nt) {
                size_t wo = ((size_t)(s * 16 + ntileMap[nt]) * 64 + lane) * 8;
                bf16x8 wh = *(const bf16x8*)&Whi[wo];
                bf16x8 wl = *(const bf16x8*)&Wlo[wo];
                acc[nt] = __builtin_amdgcn_mfma_f32_16x16x32_bf16(ah, wh, acc[nt], 0, 0, 0);
                acc[nt] = __builtin_amdgcn_mfma_f32_16x16x32_bf16(al, wh, acc[nt], 0, 0, 0);
                acc[nt] = __builtin_amdgcn_mfma_f32_16x16x32_bf16(ah, wl, acc[nt], 0, 0, 0);
            }
        }
        __syncthreads();   // LDS reads done before next iter's staging

        // ---- epilogue: D row = q*4+rr, col(acc[nt]) = ntileMap[nt]*16+cc ----
        if (wave < 2) {
            // acc[p] cols = wave*32 + p*16 + cc; acc[p+2] = same + 64 -> pack
#pragma unroll
            for (int p = 0; p < 2; ++p) {
                int c = wave * 32 + p * 16 + cc;
#pragma unroll
                for (int rr = 0; rr < 4; ++rr) {
                    uint lo = f2bf(acc[p][rr]);
                    uint hi = f2bf(acc[p + 2][rr]);
                    h2out[(size_t)(row0 + q * 4 + rr) * 64 + c] = lo | (hi << 16);
                }
            }
        } else {
#pragma unroll
            for (int nt = 0; nt < 4; ++nt) {
                int col = ((wave * 4 + nt) - 8) * 16 + cc;
#pragma unroll
                for (int rr = 0; rr < 4; ++rr) {
                    int row = row0 + q * 4 + rr;
                    z[(size_t)row * D + col] = acc[nt][rr] + bsc[nt];
                }
            }
        }
    }
}

// ---------------- per layer: out = relu?(mean_agg(h) + z) -----------------------------
// edge-parallel: block owns NT consecutive dst nodes, accumulates in LDS via float atomics.
// h packing makes both atomic adds 2-lanes/bank (free). Iterations independent -> MLP.
__global__ __launch_bounds__(256) void agg_lds_kernel(
        const uint* __restrict__ h2, const int2* __restrict__ edges,
        const int* __restrict__ offsets, const float* __restrict__ invdeg,
        const float* __restrict__ zin, float* __restrict__ out, int relu) {
    __shared__ float sacc[NT * 128];
    int tid = threadIdx.x;
    int wave = tid >> 6;
    int lane = tid & 63;
    int node0 = blockIdx.x * NT;

    for (int i = tid; i < NT * 128; i += 256) sacc[i] = 0.f;

    int start = offsets[node0];
    int end = (node0 + NT < N_NODES) ? offsets[node0 + NT] : N_EDGES;
    __syncthreads();

    int e = start + wave;
    if (e < end) {
        int2 ed = edges[e];
        for (;;) {
            int en = e + 4;
            int2 edn;
            bool has = en < end;
            if (has) edn = edges[en];          // prefetch next edge
            uint u = h2[(size_t)ed.x * 64 + lane];
            int base = (ed.y - node0) * 128 + lane;
            atomicAdd(&sacc[base], __uint_as_float(u << 16));
            atomicAdd(&sacc[base + 64], __uint_as_float(u & 0xffff0000u));
            if (!has) break;
            ed = edn; e = en;
        }
    }
    __syncthreads();

    int c4 = (tid & 31) * 4;
    for (int local = tid >> 5; local < NT; local += 8) {
        int node = node0 + local;
        float inv = invdeg[node];
        float4 s = *(float4*)&sacc[local * 128 + c4];
        float4 zv = *(const float4*)&zin[(size_t)node * 128 + c4];
        float4 o;
        o.x = s.x * inv + zv.x;
        o.y = s.y * inv + zv.y;
        o.z = s.z * inv + zv.z;
        o.w = s.w * inv + zv.w;
        if (relu) {
            o.x = fmaxf(o.x, 0.f); o.y = fmaxf(o.y, 0.f);
            o.z = fmaxf(o.z, 0.f); o.w = fmaxf(o.w, 0.f);
        }
        *(float4*)&out[(size_t)node * 128 + c4] = o;
    }
}

extern "C" void kernel_launch(void* const* d_in, const int* in_sizes, int n_in,
                              void* d_out, int out_size, void* d_ws, size_t ws_size,
                              hipStream_t stream) {
    const float* x  = (const float*)d_in[0];
    const float* Wl = (const float*)d_in[1];
    const float* Wr = (const float*)d_in[2];
    const float* b  = (const float*)d_in[3];
    const int*   ei = (const int*)d_in[4];
    const int* src = ei;
    const int* dst = ei + N_EDGES;
    float* out = (float*)d_out;

    char* w = (char*)d_ws;
    auto alloc = [&](size_t bytes) -> char* {
        char* p = w;
        w += (bytes + 255) & ~(size_t)255;
        return p;
    };
    float*  zx        = (float*)alloc((size_t)N_NODES * D * 4);   // z buffer == activation buffer
    uint*   hbuf      = (uint*)alloc((size_t)N_NODES * 64 * 4);   // packed bf16 col-pairs
    ushort* Whi       = (ushort*)alloc((size_t)N_LAYERS * 4 * 16 * 64 * 8 * 2);
    ushort* Wlo       = (ushort*)alloc((size_t)N_LAYERS * 4 * 16 * 64 * 8 * 2);
    int*    deg       = (int*)alloc((size_t)N_NODES * 4);
    int*    offsets   = (int*)alloc((size_t)N_NODES * 4);
    int*    fill      = (int*)alloc((size_t)N_NODES * 4);
    int2*   edges     = (int2*)alloc((size_t)N_EDGES * 8);
    int*    blockSums = (int*)alloc(128 * 4);
    int*    blockOffs = (int*)alloc(128 * 4);
    float*  invdeg    = (float*)alloc((size_t)N_NODES * 4);

    hipMemsetAsync(deg, 0, (size_t)N_NODES * 4, stream);
    hipMemsetAsync(fill, 0, (size_t)N_NODES * 4, stream);

    hist_kernel<<<(N_EDGES + 255) / 256, 256, 0, stream>>>(dst, deg);
    scanA_kernel<<<SCAN_BLOCKS, 1024, 0, stream>>>(deg, offsets, blockSums);
    scanB_kernel<<<1, 128, 0, stream>>>(blockSums, blockOffs);
    scanC_kernel<<<SCAN_BLOCKS, 1024, 0, stream>>>(offsets, blockOffs);
    invdeg_kernel<<<(N_NODES + 255) / 256, 256, 0, stream>>>(deg, invdeg);
    scatter_kernel<<<(N_EDGES + 255) / 256, 256, 0, stream>>>(src, dst, offsets, fill, edges);
    wsplit_kernel<<<(N_LAYERS * 4 * 16 * 64 + 255) / 256, 256, 0, stream>>>(Wl, Wr, Whi, Wlo);

    const float* cur = x;
    for (int L = 0; L < N_LAYERS; ++L) {
        size_t woff = (size_t)L * 4 * 16 * 64 * 8;
        gemm_hz<<<1568, 256, 0, stream>>>(cur, Whi + woff, Wlo + woff,
                                          b + (size_t)L * D, hbuf, zx);
        float* o = (L == N_LAYERS - 1) ? out : zx;
        agg_lds_kernel<<<N_NODES / NT, 256, 0, stream>>>(
            hbuf, edges, offsets, invdeg, zx, o, (L < N_LAYERS - 1) ? 1 : 0);
        cur = o;
    }
}

// Round 4
// 884.360 us; speedup vs baseline: 5.4459x; 5.4459x over previous
//
#include <hip/hip_runtime.h>
#include <hip/hip_bf16.h>

#define N_NODES 100000
#define N_EDGES 625000
#define D 128
#define N_LAYERS 10
#define SCAN_BLOCKS 98   // ceil(100000/1024)

typedef __attribute__((ext_vector_type(8))) short bf16x8;
typedef __attribute__((ext_vector_type(4))) float floatx4;

static __device__ __forceinline__ ushort f2bf(float f) {
    uint u = __float_as_uint(f);
    u += 0x7fff + ((u >> 16) & 1);   // round-to-nearest-even
    return (ushort)(u >> 16);
}
static __device__ __forceinline__ float bf2f(ushort h) {
    return __uint_as_float(((uint)h) << 16);
}

// ---------------- CSR build (once per call) ----------------

__global__ void hist_kernel(const int* __restrict__ dst, int* __restrict__ deg) {
    int e = blockIdx.x * blockDim.x + threadIdx.x;
    if (e < N_EDGES) atomicAdd(&deg[dst[e]], 1);
}

__global__ void scanA_kernel(const int* __restrict__ deg, int* __restrict__ offsets,
                             int* __restrict__ blockSums) {
    __shared__ int s[1024];
    int tid = threadIdx.x;
    int i = blockIdx.x * 1024 + tid;
    int v = (i < N_NODES) ? deg[i] : 0;
    s[tid] = v;
    __syncthreads();
    for (int d = 1; d < 1024; d <<= 1) {
        int t = (tid >= d) ? s[tid - d] : 0;
        __syncthreads();
        s[tid] += t;
        __syncthreads();
    }
    if (i < N_NODES) offsets[i] = s[tid] - v;   // exclusive
    if (tid == 1023) blockSums[blockIdx.x] = s[1023];
}

__global__ void scanB_kernel(const int* __restrict__ blockSums, int* __restrict__ blockOffsets) {
    __shared__ int s[128];
    int tid = threadIdx.x;
    int v = (tid < SCAN_BLOCKS) ? blockSums[tid] : 0;
    s[tid] = v;
    __syncthreads();
    for (int d = 1; d < 128; d <<= 1) {
        int t = (tid >= d) ? s[tid - d] : 0;
        __syncthreads();
        s[tid] += t;
        __syncthreads();
    }
    blockOffsets[tid] = s[tid] - v;             // exclusive
}

__global__ void scanC_kernel(int* __restrict__ offsets, const int* __restrict__ blockOffsets) {
    int i = blockIdx.x * 1024 + threadIdx.x;
    if (i < N_NODES) offsets[i] += blockOffsets[blockIdx.x];
}

__global__ void invdeg_kernel(const int* __restrict__ deg, float* __restrict__ invdeg) {
    int i = blockIdx.x * blockDim.x + threadIdx.x;
    if (i < N_NODES) {
        int d = deg[i];
        invdeg[i] = 1.0f / (float)(d > 0 ? d : 1);
    }
}

__global__ void scatter_kernel(const int* __restrict__ src, const int* __restrict__ dst,
                               const int* __restrict__ offsets, int* __restrict__ fill,
                               int* __restrict__ srcSorted) {
    int e = blockIdx.x * blockDim.x + threadIdx.x;
    if (e < N_EDGES) {
        int d_ = dst[e];
        int pos = offsets[d_] + atomicAdd(&fill[d_], 1);
        srcSorted[pos] = src[e];
    }
}

// ---------------- W hi/lo split into B-fragment layout (once per call) ----------------
// layout: (((layer*4 + s)*16 + ntile)*64 + lane)*8, element j: k = s*32+(lane>>4)*8+j,
// n = ntile*16 + (lane&15); n<128 -> Wl, else Wr (col n-128)
__global__ void wsplit_kernel(const float* __restrict__ Wl, const float* __restrict__ Wr,
                              ushort* __restrict__ Whi, ushort* __restrict__ Wlo) {
    int t = blockIdx.x * blockDim.x + threadIdx.x;
    if (t >= N_LAYERS * 4 * 16 * 64) return;
    int lane  = t & 63;
    int ntile = (t >> 6) & 15;
    int s     = (t >> 10) & 3;
    int layer = t >> 12;
    int n = ntile * 16 + (lane & 15);
    int kbase = s * 32 + (lane >> 4) * 8;
    const float* W = (n < 128) ? (Wl + (size_t)layer * D * D + n)
                               : (Wr + (size_t)layer * D * D + (n - 128));
    size_t off = (size_t)t * 8;
#pragma unroll
    for (int j = 0; j < 8; ++j) {
        float w = W[(size_t)(kbase + j) * D];
        ushort hh = f2bf(w);
        Whi[off + j] = hh;
        Wlo[off + j] = f2bf(w - bf2f(hh));
    }
}

// ---------------- per layer: h = x@Wl (bf16 col-pair packed), z = x@Wr + b (fp32) -------
// block 256 = 4 waves; M-tile 32 rows (two 16-row subtiles share W fragments), K=128.
// waves 0,1 own ntiles {0,1,4,5}/{2,3,6,7}: lane holds col pairs (c, c+64) and writes
// h packed: uint j of a row = bf16(col j) | bf16(col j+64) << 16.
// waves 2,3 own ntiles 8..15 -> z (fp32 + bias), in-place-safe over X.
__global__ __launch_bounds__(256) void gemm_hz(
        const float* __restrict__ X, const ushort* __restrict__ Whi,
        const ushort* __restrict__ Wlo, const float* __restrict__ bias,
        uint* __restrict__ h2out, float* __restrict__ z) {
    __shared__ ushort Ahi[2][4 * 64 * 8];   // [subtile][s][lane ^ (s<<2)][8]  (8 KB each)
    __shared__ ushort Alo[2][4 * 64 * 8];

    int tid  = threadIdx.x;
    int lane = tid & 63;
    int wave = tid >> 6;

    // staging indices: thread (r, t0) loads A[row0+r][t0*8 .. t0*8+7] (and row0+16+r)
    int r    = tid >> 4;       // 0..15
    int t0   = tid & 15;       // 0..15 (8-float chunk)
    int s_st = t0 >> 2;
    int q_st = t0 & 3;
    int lanep = (q_st << 4) | r;
    int stIdx = (s_st * 64 + (lanep ^ (s_st << 2))) * 8;

    int q  = lane >> 4;        // D-frag quad
    int cc = lane & 15;        // D-frag col-in-tile

    int ntileMap[4];
#pragma unroll
    for (int nt = 0; nt < 4; ++nt)
        ntileMap[nt] = (wave < 2) ? (wave * 2 + (nt & 1) + ((nt >> 1) << 2))
                                  : (wave * 4 + nt);

    float bsc[4] = {0.f, 0.f, 0.f, 0.f};
    if (wave >= 2) {
#pragma unroll
        for (int nt = 0; nt < 4; ++nt)
            bsc[nt] = bias[((wave * 4 + nt) - 8) * 16 + cc];
    }

    for (int mt = blockIdx.x; mt < N_NODES / 32; mt += gridDim.x) {
        int row0 = mt * 32;
        // ---- stage both 16-row subtiles, split hi/lo ----
#pragma unroll
        for (int st = 0; st < 2; ++st) {
            const float* xp = X + (size_t)(row0 + st * 16 + r) * D + t0 * 8;
            float4 v0 = *(const float4*)xp;
            float4 v1 = *(const float4*)(xp + 4);
            float a[8] = {v0.x, v0.y, v0.z, v0.w, v1.x, v1.y, v1.z, v1.w};
            ushort hi8[8], lo8[8];
#pragma unroll
            for (int j = 0; j < 8; ++j) {
                ushort hh = f2bf(a[j]);
                hi8[j] = hh;
                lo8[j] = f2bf(a[j] - bf2f(hh));
            }
            *(bf16x8*)&Ahi[st][stIdx] = *(bf16x8*)hi8;
            *(bf16x8*)&Alo[st][stIdx] = *(bf16x8*)lo8;
        }
        __syncthreads();

        // ---- MFMA: 3-pass hi/lo split, W fragments shared across subtiles ----
        floatx4 acc0[4], acc1[4];
#pragma unroll
        for (int nt = 0; nt < 4; ++nt) {
            acc0[nt] = (floatx4){0.f, 0.f, 0.f, 0.f};
            acc1[nt] = (floatx4){0.f, 0.f, 0.f, 0.f};
        }
#pragma unroll
        for (int s = 0; s < 4; ++s) {
            int aIdx = (s * 64 + (lane ^ (s << 2))) * 8;
            bf16x8 ah0 = *(const bf16x8*)&Ahi[0][aIdx];
            bf16x8 al0 = *(const bf16x8*)&Alo[0][aIdx];
            bf16x8 ah1 = *(const bf16x8*)&Ahi[1][aIdx];
            bf16x8 al1 = *(const bf16x8*)&Alo[1][aIdx];
#pragma unroll
            for (int nt = 0; nt < 4; ++nt) {
                size_t wo = ((size_t)(s * 16 + ntileMap[nt]) * 64 + lane) * 8;
                bf16x8 wh = *(const bf16x8*)&Whi[wo];
                bf16x8 wl = *(const bf16x8*)&Wlo[wo];
                acc0[nt] = __builtin_amdgcn_mfma_f32_16x16x32_bf16(ah0, wh, acc0[nt], 0, 0, 0);
                acc0[nt] = __builtin_amdgcn_mfma_f32_16x16x32_bf16(al0, wh, acc0[nt], 0, 0, 0);
                acc0[nt] = __builtin_amdgcn_mfma_f32_16x16x32_bf16(ah0, wl, acc0[nt], 0, 0, 0);
                acc1[nt] = __builtin_amdgcn_mfma_f32_16x16x32_bf16(ah1, wh, acc1[nt], 0, 0, 0);
                acc1[nt] = __builtin_amdgcn_mfma_f32_16x16x32_bf16(al1, wh, acc1[nt], 0, 0, 0);
                acc1[nt] = __builtin_amdgcn_mfma_f32_16x16x32_bf16(ah1, wl, acc1[nt], 0, 0, 0);
            }
        }
        __syncthreads();   // LDS reads done before next iter's staging

        // ---- epilogue: D row = q*4+rr, col(acc[nt]) = ntileMap[nt]*16+cc ----
#pragma unroll
        for (int st = 0; st < 2; ++st) {
            floatx4* acc = st ? acc1 : acc0;
            int rowb = row0 + st * 16;
            if (wave < 2) {
                // acc[p] cols = wave*32 + p*16 + cc; acc[p+2] = same + 64 -> pack
#pragma unroll
                for (int p = 0; p < 2; ++p) {
                    int c = wave * 32 + p * 16 + cc;
#pragma unroll
                    for (int rr = 0; rr < 4; ++rr) {
                        uint lo = f2bf(acc[p][rr]);
                        uint hi = f2bf(acc[p + 2][rr]);
                        h2out[(size_t)(rowb + q * 4 + rr) * 64 + c] = lo | (hi << 16);
                    }
                }
            } else {
#pragma unroll
                for (int nt = 0; nt < 4; ++nt) {
                    int col = ((wave * 4 + nt) - 8) * 16 + cc;
#pragma unroll
                    for (int rr = 0; rr < 4; ++rr) {
                        int row = rowb + q * 4 + rr;
                        z[(size_t)row * D + col] = acc[nt][rr] + bsc[nt];
                    }
                }
            }
        }
    }
}

// ---------------- per layer: out = relu?(mean_agg(h) + z) -----------------------------
// node-parallel gather, one wave per node; neighbor indices preloaded into lanes, then
// batches of 8 independent row-gathers (dummy slots repeat neighbor 0 -> L1 hits, masked).
__global__ __launch_bounds__(256) void agg_add_kernel(
        const uint* __restrict__ h2, const int* __restrict__ srcSorted,
        const int* __restrict__ offsets, const int* __restrict__ deg,
        const float* __restrict__ invdeg, const float* __restrict__ zin,
        float* __restrict__ out, int relu) {
    int node = blockIdx.x * 4 + (threadIdx.x >> 6);
    int lane = threadIdx.x & 63;
    int off = offsets[node];
    int cnt = deg[node];
    float sx = 0.f, sy = 0.f;
    if (cnt > 0) {
        int nv = cnt < 64 ? cnt : 64;
        int idxv = srcSorted[off + ((lane < nv) ? lane : 0)];
        for (int k = 0; k < nv; k += 8) {
            int sidx[8];
#pragma unroll
            for (int j = 0; j < 8; ++j) {
                int kk = k + j;
                sidx[j] = __shfl(idxv, (kk < nv) ? kk : 0, 64);
            }
            uint u[8];
#pragma unroll
            for (int j = 0; j < 8; ++j)
                u[j] = h2[(size_t)sidx[j] * 64 + lane];
#pragma unroll
            for (int j = 0; j < 8; ++j) {
                float m = ((k + j) < nv) ? 1.f : 0.f;
                sx += m * __uint_as_float(u[j] << 16);
                sy += m * __uint_as_float(u[j] & 0xffff0000u);
            }
        }
        for (int k = 64; k < cnt; ++k) {   // ultra-rare tail (deg > 64)
            int s = srcSorted[off + k];
            uint u = h2[(size_t)s * 64 + lane];
            sx += __uint_as_float(u << 16);
            sy += __uint_as_float(u & 0xffff0000u);
        }
    }
    float inv = invdeg[node];
    float ox = sx * inv + zin[(size_t)node * 128 + lane];
    float oy = sy * inv + zin[(size_t)node * 128 + 64 + lane];
    if (relu) { ox = fmaxf(ox, 0.f); oy = fmaxf(oy, 0.f); }
    out[(size_t)node * 128 + lane] = ox;
    out[(size_t)node * 128 + 64 + lane] = oy;
}

extern "C" void kernel_launch(void* const* d_in, const int* in_sizes, int n_in,
                              void* d_out, int out_size, void* d_ws, size_t ws_size,
                              hipStream_t stream) {
    const float* x  = (const float*)d_in[0];
    const float* Wl = (const float*)d_in[1];
    const float* Wr = (const float*)d_in[2];
    const float* b  = (const float*)d_in[3];
    const int*   ei = (const int*)d_in[4];
    const int* src = ei;
    const int* dst = ei + N_EDGES;
    float* out = (float*)d_out;

    char* w = (char*)d_ws;
    auto alloc = [&](size_t bytes) -> char* {
        char* p = w;
        w += (bytes + 255) & ~(size_t)255;
        return p;
    };
    float*  zx        = (float*)alloc((size_t)N_NODES * D * 4);   // z buffer == activation buffer
    uint*   hbuf      = (uint*)alloc((size_t)N_NODES * 64 * 4);   // packed bf16 col-pairs
    ushort* Whi       = (ushort*)alloc((size_t)N_LAYERS * 4 * 16 * 64 * 8 * 2);
    ushort* Wlo       = (ushort*)alloc((size_t)N_LAYERS * 4 * 16 * 64 * 8 * 2);
    int*    deg       = (int*)alloc((size_t)N_NODES * 4);
    int*    offsets   = (int*)alloc((size_t)N_NODES * 4);
    int*    fill      = (int*)alloc((size_t)N_NODES * 4);
    int*    srcSorted = (int*)alloc((size_t)N_EDGES * 4);
    int*    blockSums = (int*)alloc(128 * 4);
    int*    blockOffs = (int*)alloc(128 * 4);
    float*  invdeg    = (float*)alloc((size_t)N_NODES * 4);

    hipMemsetAsync(deg, 0, (size_t)N_NODES * 4, stream);
    hipMemsetAsync(fill, 0, (size_t)N_NODES * 4, stream);

    hist_kernel<<<(N_EDGES + 255) / 256, 256, 0, stream>>>(dst, deg);
    scanA_kernel<<<SCAN_BLOCKS, 1024, 0, stream>>>(deg, offsets, blockSums);
    scanB_kernel<<<1, 128, 0, stream>>>(blockSums, blockOffs);
    scanC_kernel<<<SCAN_BLOCKS, 1024, 0, stream>>>(offsets, blockOffs);
    invdeg_kernel<<<(N_NODES + 255) / 256, 256, 0, stream>>>(deg, invdeg);
    scatter_kernel<<<(N_EDGES + 255) / 256, 256, 0, stream>>>(src, dst, offsets, fill, srcSorted);
    wsplit_kernel<<<(N_LAYERS * 4 * 16 * 64 + 255) / 256, 256, 0, stream>>>(Wl, Wr, Whi, Wlo);

    const float* cur = x;
    for (int L = 0; L < N_LAYERS; ++L) {
        size_t woff = (size_t)L * 4 * 16 * 64 * 8;
        gemm_hz<<<N_NODES / 32, 256, 0, stream>>>(cur, Whi + woff, Wlo + woff,
                                                  b + (size_t)L * D, hbuf, zx);
        float* o = (L == N_LAYERS - 1) ? out : zx;
        agg_add_kernel<<<N_NODES / 4, 256, 0, stream>>>(
            hbuf, srcSorted, offsets, deg, invdeg, zx, o, (L < N_LAYERS - 1) ? 1 : 0);
        cur = o;
    }
}

// Round 5
// 823.860 us; speedup vs baseline: 5.8458x; 1.0734x over previous
//
#include <hip/hip_runtime.h>
#include <hip/hip_bf16.h>

#define N_NODES 100000
#define N_EDGES 625000
#define D 128
#define N_LAYERS 10
#define SCAN_BLOCKS 98   // ceil(100000/1024)

typedef __attribute__((ext_vector_type(8))) short bf16x8;
typedef __attribute__((ext_vector_type(4))) float floatx4;

static __device__ __forceinline__ ushort f2bf(float f) {
    uint u = __float_as_uint(f);
    u += 0x7fff + ((u >> 16) & 1);   // round-to-nearest-even
    return (ushort)(u >> 16);
}
static __device__ __forceinline__ float bf2f(ushort h) {
    return __uint_as_float(((uint)h) << 16);
}

// ---------------- CSR build (once per call) ----------------

__global__ void hist_kernel(const int* __restrict__ dst, int* __restrict__ deg) {
    int e = blockIdx.x * blockDim.x + threadIdx.x;
    if (e < N_EDGES) atomicAdd(&deg[dst[e]], 1);
}

__global__ void scanA_kernel(const int* __restrict__ deg, int* __restrict__ offsets,
                             int* __restrict__ blockSums) {
    __shared__ int s[1024];
    int tid = threadIdx.x;
    int i = blockIdx.x * 1024 + tid;
    int v = (i < N_NODES) ? deg[i] : 0;
    s[tid] = v;
    __syncthreads();
    for (int d = 1; d < 1024; d <<= 1) {
        int t = (tid >= d) ? s[tid - d] : 0;
        __syncthreads();
        s[tid] += t;
        __syncthreads();
    }
    if (i < N_NODES) offsets[i] = s[tid] - v;   // exclusive
    if (tid == 1023) blockSums[blockIdx.x] = s[1023];
}

__global__ void scanB_kernel(const int* __restrict__ blockSums, int* __restrict__ blockOffsets) {
    __shared__ int s[128];
    int tid = threadIdx.x;
    int v = (tid < SCAN_BLOCKS) ? blockSums[tid] : 0;
    s[tid] = v;
    __syncthreads();
    for (int d = 1; d < 128; d <<= 1) {
        int t = (tid >= d) ? s[tid - d] : 0;
        __syncthreads();
        s[tid] += t;
        __syncthreads();
    }
    blockOffsets[tid] = s[tid] - v;             // exclusive
}

__global__ void scanC_kernel(int* __restrict__ offsets, const int* __restrict__ blockOffsets) {
    int i = blockIdx.x * 1024 + threadIdx.x;
    if (i < N_NODES) offsets[i] += blockOffsets[blockIdx.x];
}

__global__ void invdeg_kernel(const int* __restrict__ deg, float* __restrict__ invdeg,
                              int* __restrict__ offsets) {
    int i = blockIdx.x * blockDim.x + threadIdx.x;
    if (i < N_NODES) {
        int d = deg[i];
        invdeg[i] = 1.0f / (float)(d > 0 ? d : 1);
    }
    if (i == 0) offsets[N_NODES] = N_EDGES;   // sentinel
}

__global__ void scatter_kernel(const int* __restrict__ src, const int* __restrict__ dst,
                               const int* __restrict__ offsets, int* __restrict__ fill,
                               int* __restrict__ srcSorted) {
    int e = blockIdx.x * blockDim.x + threadIdx.x;
    if (e < N_EDGES) {
        int d_ = dst[e];
        int pos = offsets[d_] + atomicAdd(&fill[d_], 1);
        srcSorted[pos] = src[e];
    }
}

// ---------------- W hi/lo split into B-fragment layout (once per call) ----------------
// layout: (((layer*4 + s)*16 + ntile)*64 + lane)*8, element j: k = s*32+(lane>>4)*8+j,
// n = ntile*16 + (lane&15); n<128 -> Wl, else Wr (col n-128)
__global__ void wsplit_kernel(const float* __restrict__ Wl, const float* __restrict__ Wr,
                              ushort* __restrict__ Whi, ushort* __restrict__ Wlo) {
    int t = blockIdx.x * blockDim.x + threadIdx.x;
    if (t >= N_LAYERS * 4 * 16 * 64) return;
    int lane  = t & 63;
    int ntile = (t >> 6) & 15;
    int s     = (t >> 10) & 3;
    int layer = t >> 12;
    int n = ntile * 16 + (lane & 15);
    int kbase = s * 32 + (lane >> 4) * 8;
    const float* W = (n < 128) ? (Wl + (size_t)layer * D * D + n)
                               : (Wr + (size_t)layer * D * D + (n - 128));
    size_t off = (size_t)t * 8;
#pragma unroll
    for (int j = 0; j < 8; ++j) {
        float w = W[(size_t)(kbase + j) * D];
        ushort hh = f2bf(w);
        Whi[off + j] = hh;
        Wlo[off + j] = f2bf(w - bf2f(hh));
    }
}

// ---------------- layer 0: h = x@Wl (bf16 col-pair packed), z = x@Wr + b (fp32) --------
__global__ __launch_bounds__(256) void gemm_hz(
        const float* __restrict__ X, const ushort* __restrict__ Whi,
        const ushort* __restrict__ Wlo, const float* __restrict__ bias,
        uint* __restrict__ h2out, float* __restrict__ z) {
    __shared__ ushort Ahi[2][4 * 64 * 8];
    __shared__ ushort Alo[2][4 * 64 * 8];

    int tid  = threadIdx.x;
    int lane = tid & 63;
    int wave = tid >> 6;

    int r    = tid >> 4;
    int t0   = tid & 15;
    int s_st = t0 >> 2;
    int q_st = t0 & 3;
    int lanep = (q_st << 4) | r;
    int stIdx = (s_st * 64 + (lanep ^ (s_st << 2))) * 8;

    int q  = lane >> 4;
    int cc = lane & 15;

    int ntileMap[4];
#pragma unroll
    for (int nt = 0; nt < 4; ++nt)
        ntileMap[nt] = (wave < 2) ? (wave * 2 + (nt & 1) + ((nt >> 1) << 2))
                                  : (wave * 4 + nt);

    float bsc[4] = {0.f, 0.f, 0.f, 0.f};
    if (wave >= 2) {
#pragma unroll
        for (int nt = 0; nt < 4; ++nt)
            bsc[nt] = bias[((wave * 4 + nt) - 8) * 16 + cc];
    }

    int mt = blockIdx.x;
    {
        int row0 = mt * 32;
#pragma unroll
        for (int st = 0; st < 2; ++st) {
            const float* xp = X + (size_t)(row0 + st * 16 + r) * D + t0 * 8;
            float4 v0 = *(const float4*)xp;
            float4 v1 = *(const float4*)(xp + 4);
            float a[8] = {v0.x, v0.y, v0.z, v0.w, v1.x, v1.y, v1.z, v1.w};
            ushort hi8[8], lo8[8];
#pragma unroll
            for (int j = 0; j < 8; ++j) {
                ushort hh = f2bf(a[j]);
                hi8[j] = hh;
                lo8[j] = f2bf(a[j] - bf2f(hh));
            }
            *(bf16x8*)&Ahi[st][stIdx] = *(bf16x8*)hi8;
            *(bf16x8*)&Alo[st][stIdx] = *(bf16x8*)lo8;
        }
        __syncthreads();

        floatx4 acc0[4], acc1[4];
#pragma unroll
        for (int nt = 0; nt < 4; ++nt) {
            acc0[nt] = (floatx4){0.f, 0.f, 0.f, 0.f};
            acc1[nt] = (floatx4){0.f, 0.f, 0.f, 0.f};
        }
#pragma unroll
        for (int s = 0; s < 4; ++s) {
            int aIdx = (s * 64 + (lane ^ (s << 2))) * 8;
            bf16x8 ah0 = *(const bf16x8*)&Ahi[0][aIdx];
            bf16x8 al0 = *(const bf16x8*)&Alo[0][aIdx];
            bf16x8 ah1 = *(const bf16x8*)&Ahi[1][aIdx];
            bf16x8 al1 = *(const bf16x8*)&Alo[1][aIdx];
#pragma unroll
            for (int nt = 0; nt < 4; ++nt) {
                size_t wo = ((size_t)(s * 16 + ntileMap[nt]) * 64 + lane) * 8;
                bf16x8 wh = *(const bf16x8*)&Whi[wo];
                bf16x8 wl = *(const bf16x8*)&Wlo[wo];
                acc0[nt] = __builtin_amdgcn_mfma_f32_16x16x32_bf16(ah0, wh, acc0[nt], 0, 0, 0);
                acc0[nt] = __builtin_amdgcn_mfma_f32_16x16x32_bf16(al0, wh, acc0[nt], 0, 0, 0);
                acc0[nt] = __builtin_amdgcn_mfma_f32_16x16x32_bf16(ah0, wl, acc0[nt], 0, 0, 0);
                acc1[nt] = __builtin_amdgcn_mfma_f32_16x16x32_bf16(ah1, wh, acc1[nt], 0, 0, 0);
                acc1[nt] = __builtin_amdgcn_mfma_f32_16x16x32_bf16(al1, wh, acc1[nt], 0, 0, 0);
                acc1[nt] = __builtin_amdgcn_mfma_f32_16x16x32_bf16(ah1, wl, acc1[nt], 0, 0, 0);
            }
        }

#pragma unroll
        for (int st = 0; st < 2; ++st) {
            floatx4* acc = st ? acc1 : acc0;
            int rowb = row0 + st * 16;
            if (wave < 2) {
#pragma unroll
                for (int p = 0; p < 2; ++p) {
                    int c = wave * 32 + p * 16 + cc;
#pragma unroll
                    for (int rr = 0; rr < 4; ++rr) {
                        uint lo = f2bf(acc[p][rr]);
                        uint hi = f2bf(acc[p + 2][rr]);
                        h2out[(size_t)(rowb + q * 4 + rr) * 64 + c] = lo | (hi << 16);
                    }
                }
            } else {
#pragma unroll
                for (int nt = 0; nt < 4; ++nt) {
                    int col = ((wave * 4 + nt) - 8) * 16 + cc;
#pragma unroll
                    for (int rr = 0; rr < 4; ++rr) {
                        int row = rowb + q * 4 + rr;
                        z[(size_t)row * D + col] = acc[nt][rr] + bsc[nt];
                    }
                }
            }
        }
    }
}

// ---------------- fused layer L: act = relu(mean_agg(h_{L-1}) + z_{L-1});
//                  h_L = act@Wl (packed), z_L = act@Wr + b (in-place over z) -------------
// block = 32 nodes (4 waves x 8 nodes). Gather -> split hi/lo straight into A-frag LDS.
__global__ __launch_bounds__(256) void fused_layer(
        const uint* __restrict__ h2in, const int* __restrict__ srcSorted,
        const int* __restrict__ offsets, const float* __restrict__ invdeg,
        const float* __restrict__ zio, const ushort* __restrict__ Whi,
        const ushort* __restrict__ Wlo, const float* __restrict__ bias,
        uint* __restrict__ h2out) {
    __shared__ ushort Ahi[2][4 * 64 * 8];   // 8 KB
    __shared__ ushort Alo[2][4 * 64 * 8];   // 8 KB

    int tid  = threadIdx.x;
    int lane = tid & 63;
    int wave = tid >> 6;
    int row0 = blockIdx.x * 32;

    // ---- phase 1: aggregate 8 nodes/wave, write A-fragments ----
    int n0 = row0 + wave * 8;
    int offA[9];
#pragma unroll
    for (int i = 0; i < 9; ++i) offA[i] = offsets[n0 + i];
    int off0 = offA[0];
    int total = offA[8] - off0;
    int idxv = srcSorted[min(off0 + ((lane < total) ? lane : 0), N_EDGES - 1)];

    for (int i = 0; i < 8; ++i) {
        int sRel = offA[i] - off0;
        int eRel = offA[i + 1] - off0;
        int cnt = eRel - sRel;
        float sx = 0.f, sy = 0.f;
        if (cnt > 0 && eRel <= 64) {
            for (int k = sRel; k < eRel; k += 8) {
                int sidx[8];
#pragma unroll
                for (int j = 0; j < 8; ++j) {
                    int kk = k + j;
                    sidx[j] = __shfl(idxv, (kk < eRel) ? kk : sRel, 64);
                }
                uint u[8];
#pragma unroll
                for (int j = 0; j < 8; ++j)
                    u[j] = h2in[(size_t)sidx[j] * 64 + lane];
#pragma unroll
                for (int j = 0; j < 8; ++j) {
                    float m = ((k + j) < eRel) ? 1.f : 0.f;
                    sx += m * __uint_as_float(u[j] << 16);
                    sy += m * __uint_as_float(u[j] & 0xffff0000u);
                }
            }
        } else if (cnt > 0) {
            int offn = offA[i];
            int nv = cnt < 64 ? cnt : 64;
            int idxn = srcSorted[offn + ((lane < nv) ? lane : 0)];
            for (int k = 0; k < nv; k += 8) {
                int sidx[8];
#pragma unroll
                for (int j = 0; j < 8; ++j) {
                    int kk = k + j;
                    sidx[j] = __shfl(idxn, (kk < nv) ? kk : 0, 64);
                }
                uint u[8];
#pragma unroll
                for (int j = 0; j < 8; ++j)
                    u[j] = h2in[(size_t)sidx[j] * 64 + lane];
#pragma unroll
                for (int j = 0; j < 8; ++j) {
                    float m = ((k + j) < nv) ? 1.f : 0.f;
                    sx += m * __uint_as_float(u[j] << 16);
                    sy += m * __uint_as_float(u[j] & 0xffff0000u);
                }
            }
            for (int k = 64; k < cnt; ++k) {
                int s = srcSorted[offn + k];
                uint u = h2in[(size_t)s * 64 + lane];
                sx += __uint_as_float(u << 16);
                sy += __uint_as_float(u & 0xffff0000u);
            }
        }
        int node = n0 + i;
        float inv = invdeg[node];
        float ox = fmaxf(sx * inv + zio[(size_t)node * D + lane], 0.f);
        float oy = fmaxf(sy * inv + zio[(size_t)node * D + 64 + lane], 0.f);

        int local = wave * 8 + i;
        int st = local >> 4;
        int m = local & 15;
        // col c = lane
        {
            int c = lane;
            int s_ = c >> 5, q_ = (c >> 3) & 3, j_ = c & 7;
            int elem = (s_ * 64 + (((q_ << 4) | m) ^ (s_ << 2))) * 8 + j_;
            ushort hh = f2bf(ox);
            Ahi[st][elem] = hh;
            Alo[st][elem] = f2bf(ox - bf2f(hh));
        }
        // col c = lane + 64
        {
            int c = lane + 64;
            int s_ = c >> 5, q_ = (c >> 3) & 3, j_ = c & 7;
            int elem = (s_ * 64 + (((q_ << 4) | m) ^ (s_ << 2))) * 8 + j_;
            ushort hh = f2bf(oy);
            Ahi[st][elem] = hh;
            Alo[st][elem] = f2bf(oy - bf2f(hh));
        }
    }
    __syncthreads();

    // ---- phase 2: MFMA (identical to gemm_hz core) ----
    int q  = lane >> 4;
    int cc = lane & 15;
    int ntileMap[4];
#pragma unroll
    for (int nt = 0; nt < 4; ++nt)
        ntileMap[nt] = (wave < 2) ? (wave * 2 + (nt & 1) + ((nt >> 1) << 2))
                                  : (wave * 4 + nt);
    float bsc[4] = {0.f, 0.f, 0.f, 0.f};
    if (wave >= 2) {
#pragma unroll
        for (int nt = 0; nt < 4; ++nt)
            bsc[nt] = bias[((wave * 4 + nt) - 8) * 16 + cc];
    }

    floatx4 acc0[4], acc1[4];
#pragma unroll
    for (int nt = 0; nt < 4; ++nt) {
        acc0[nt] = (floatx4){0.f, 0.f, 0.f, 0.f};
        acc1[nt] = (floatx4){0.f, 0.f, 0.f, 0.f};
    }
#pragma unroll
    for (int s = 0; s < 4; ++s) {
        int aIdx = (s * 64 + (lane ^ (s << 2))) * 8;
        bf16x8 ah0 = *(const bf16x8*)&Ahi[0][aIdx];
        bf16x8 al0 = *(const bf16x8*)&Alo[0][aIdx];
        bf16x8 ah1 = *(const bf16x8*)&Ahi[1][aIdx];
        bf16x8 al1 = *(const bf16x8*)&Alo[1][aIdx];
#pragma unroll
        for (int nt = 0; nt < 4; ++nt) {
            size_t wo = ((size_t)(s * 16 + ntileMap[nt]) * 64 + lane) * 8;
            bf16x8 wh = *(const bf16x8*)&Whi[wo];
            bf16x8 wl = *(const bf16x8*)&Wlo[wo];
            acc0[nt] = __builtin_amdgcn_mfma_f32_16x16x32_bf16(ah0, wh, acc0[nt], 0, 0, 0);
            acc0[nt] = __builtin_amdgcn_mfma_f32_16x16x32_bf16(al0, wh, acc0[nt], 0, 0, 0);
            acc0[nt] = __builtin_amdgcn_mfma_f32_16x16x32_bf16(ah0, wl, acc0[nt], 0, 0, 0);
            acc1[nt] = __builtin_amdgcn_mfma_f32_16x16x32_bf16(ah1, wh, acc1[nt], 0, 0, 0);
            acc1[nt] = __builtin_amdgcn_mfma_f32_16x16x32_bf16(al1, wh, acc1[nt], 0, 0, 0);
            acc1[nt] = __builtin_amdgcn_mfma_f32_16x16x32_bf16(ah1, wl, acc1[nt], 0, 0, 0);
        }
    }

#pragma unroll
    for (int st = 0; st < 2; ++st) {
        floatx4* acc = st ? acc1 : acc0;
        int rowb = row0 + st * 16;
        if (wave < 2) {
#pragma unroll
            for (int p = 0; p < 2; ++p) {
                int c = wave * 32 + p * 16 + cc;
#pragma unroll
                for (int rr = 0; rr < 4; ++rr) {
                    uint lo = f2bf(acc[p][rr]);
                    uint hi = f2bf(acc[p + 2][rr]);
                    h2out[(size_t)(rowb + q * 4 + rr) * 64 + c] = lo | (hi << 16);
                }
            }
        } else {
#pragma unroll
            for (int nt = 0; nt < 4; ++nt) {
                int col = ((wave * 4 + nt) - 8) * 16 + cc;
#pragma unroll
                for (int rr = 0; rr < 4; ++rr) {
                    int row = rowb + q * 4 + rr;
                    ((float*)zio)[(size_t)row * D + col] = acc[nt][rr] + bsc[nt];
                }
            }
        }
    }
}

// ---------------- final: out = mean_agg(h9) + z9 (no relu) ----------------------------
__global__ __launch_bounds__(256) void agg_add_kernel(
        const uint* __restrict__ h2, const int* __restrict__ srcSorted,
        const int* __restrict__ offsets, const int* __restrict__ deg,
        const float* __restrict__ invdeg, const float* __restrict__ zin,
        float* __restrict__ out) {
    int node = blockIdx.x * 4 + (threadIdx.x >> 6);
    int lane = threadIdx.x & 63;
    int off = offsets[node];
    int cnt = deg[node];
    float sx = 0.f, sy = 0.f;
    if (cnt > 0) {
        int nv = cnt < 64 ? cnt : 64;
        int idxv = srcSorted[off + ((lane < nv) ? lane : 0)];
        for (int k = 0; k < nv; k += 8) {
            int sidx[8];
#pragma unroll
            for (int j = 0; j < 8; ++j) {
                int kk = k + j;
                sidx[j] = __shfl(idxv, (kk < nv) ? kk : 0, 64);
            }
            uint u[8];
#pragma unroll
            for (int j = 0; j < 8; ++j)
                u[j] = h2[(size_t)sidx[j] * 64 + lane];
#pragma unroll
            for (int j = 0; j < 8; ++j) {
                float m = ((k + j) < nv) ? 1.f : 0.f;
                sx += m * __uint_as_float(u[j] << 16);
                sy += m * __uint_as_float(u[j] & 0xffff0000u);
            }
        }
        for (int k = 64; k < cnt; ++k) {
            int s = srcSorted[off + k];
            uint u = h2[(size_t)s * 64 + lane];
            sx += __uint_as_float(u << 16);
            sy += __uint_as_float(u & 0xffff0000u);
        }
    }
    float inv = invdeg[node];
    out[(size_t)node * 128 + lane] = sx * inv + zin[(size_t)node * 128 + lane];
    out[(size_t)node * 128 + 64 + lane] = sy * inv + zin[(size_t)node * 128 + 64 + lane];
}

extern "C" void kernel_launch(void* const* d_in, const int* in_sizes, int n_in,
                              void* d_out, int out_size, void* d_ws, size_t ws_size,
                              hipStream_t stream) {
    const float* x  = (const float*)d_in[0];
    const float* Wl = (const float*)d_in[1];
    const float* Wr = (const float*)d_in[2];
    const float* b  = (const float*)d_in[3];
    const int*   ei = (const int*)d_in[4];
    const int* src = ei;
    const int* dst = ei + N_EDGES;
    float* out = (float*)d_out;

    char* w = (char*)d_ws;
    auto alloc = [&](size_t bytes) -> char* {
        char* p = w;
        w += (bytes + 255) & ~(size_t)255;
        return p;
    };
    float*  zx        = (float*)alloc((size_t)N_NODES * D * 4);
    uint*   hbufA     = (uint*)alloc((size_t)N_NODES * 64 * 4);
    uint*   hbufB     = (uint*)alloc((size_t)N_NODES * 64 * 4);
    ushort* Whi       = (ushort*)alloc((size_t)N_LAYERS * 4 * 16 * 64 * 8 * 2);
    ushort* Wlo       = (ushort*)alloc((size_t)N_LAYERS * 4 * 16 * 64 * 8 * 2);
    int*    deg       = (int*)alloc((size_t)N_NODES * 4);
    int*    offsets   = (int*)alloc((size_t)(N_NODES + 1) * 4);
    int*    fill      = (int*)alloc((size_t)N_NODES * 4);
    int*    srcSorted = (int*)alloc((size_t)N_EDGES * 4);
    int*    blockSums = (int*)alloc(128 * 4);
    int*    blockOffs = (int*)alloc(128 * 4);
    float*  invdeg    = (float*)alloc((size_t)N_NODES * 4);

    hipMemsetAsync(deg, 0, (size_t)N_NODES * 4, stream);
    hipMemsetAsync(fill, 0, (size_t)N_NODES * 4, stream);

    hist_kernel<<<(N_EDGES + 255) / 256, 256, 0, stream>>>(dst, deg);
    scanA_kernel<<<SCAN_BLOCKS, 1024, 0, stream>>>(deg, offsets, blockSums);
    scanB_kernel<<<1, 128, 0, stream>>>(blockSums, blockOffs);
    scanC_kernel<<<SCAN_BLOCKS, 1024, 0, stream>>>(offsets, blockOffs);
    invdeg_kernel<<<(N_NODES + 255) / 256, 256, 0, stream>>>(deg, invdeg, offsets);
    scatter_kernel<<<(N_EDGES + 255) / 256, 256, 0, stream>>>(src, dst, offsets, fill, srcSorted);
    wsplit_kernel<<<(N_LAYERS * 4 * 16 * 64 + 255) / 256, 256, 0, stream>>>(Wl, Wr, Whi, Wlo);

    // layer 0
    gemm_hz<<<N_NODES / 32, 256, 0, stream>>>(x, Whi, Wlo, b, hbufA, zx);
    // layers 1..9 fused
    uint* hin = hbufA;
    uint* hout = hbufB;
    for (int L = 1; L < N_LAYERS; ++L) {
        size_t woff = (size_t)L * 4 * 16 * 64 * 8;
        fused_layer<<<N_NODES / 32, 256, 0, stream>>>(
            hin, srcSorted, offsets, invdeg, zx,
            Whi + woff, Wlo + woff, b + (size_t)L * D, hout);
        uint* t = hin; hin = hout; hout = t;
    }
    // final aggregation (h9 is in `hin` after the swap)
    agg_add_kernel<<<N_NODES / 4, 256, 0, stream>>>(
        hin, srcSorted, offsets, deg, invdeg, zx, out);
}

// Round 6
// 817.902 us; speedup vs baseline: 5.8884x; 1.0073x over previous
//
#include <hip/hip_runtime.h>
#include <hip/hip_bf16.h>

#define N_NODES 100000
#define N_EDGES 625000
#define D 128
#define N_LAYERS 10
#define SCAN_BLOCKS 98   // ceil(100000/1024)

typedef __attribute__((ext_vector_type(8))) short bf16x8;
typedef __attribute__((ext_vector_type(4))) float floatx4;

static __device__ __forceinline__ ushort f2bf(float f) {
    uint u = __float_as_uint(f);
    u += 0x7fff + ((u >> 16) & 1);   // round-to-nearest-even
    return (ushort)(u >> 16);
}
static __device__ __forceinline__ float bf2f(ushort h) {
    return __uint_as_float(((uint)h) << 16);
}

// ---------------- CSR build (once per call) ----------------

__global__ void hist_kernel(const int* __restrict__ dst, int* __restrict__ deg) {
    int e = blockIdx.x * blockDim.x + threadIdx.x;
    if (e < N_EDGES) atomicAdd(&deg[dst[e]], 1);
}

__global__ void scanA_kernel(const int* __restrict__ deg, int* __restrict__ offsets,
                             int* __restrict__ blockSums) {
    __shared__ int s[1024];
    int tid = threadIdx.x;
    int i = blockIdx.x * 1024 + tid;
    int v = (i < N_NODES) ? deg[i] : 0;
    s[tid] = v;
    __syncthreads();
    for (int d = 1; d < 1024; d <<= 1) {
        int t = (tid >= d) ? s[tid - d] : 0;
        __syncthreads();
        s[tid] += t;
        __syncthreads();
    }
    if (i < N_NODES) offsets[i] = s[tid] - v;   // exclusive
    if (tid == 1023) blockSums[blockIdx.x] = s[1023];
}

__global__ void scanB_kernel(const int* __restrict__ blockSums, int* __restrict__ blockOffsets) {
    __shared__ int s[128];
    int tid = threadIdx.x;
    int v = (tid < SCAN_BLOCKS) ? blockSums[tid] : 0;
    s[tid] = v;
    __syncthreads();
    for (int d = 1; d < 128; d <<= 1) {
        int t = (tid >= d) ? s[tid - d] : 0;
        __syncthreads();
        s[tid] += t;
        __syncthreads();
    }
    blockOffsets[tid] = s[tid] - v;             // exclusive
}

__global__ void scanC_kernel(int* __restrict__ offsets, const int* __restrict__ blockOffsets) {
    int i = blockIdx.x * 1024 + threadIdx.x;
    if (i < N_NODES) offsets[i] += blockOffsets[blockIdx.x];
}

__global__ void invdeg_kernel(const int* __restrict__ deg, float* __restrict__ invdeg,
                              int* __restrict__ offsets) {
    int i = blockIdx.x * blockDim.x + threadIdx.x;
    if (i < N_NODES) {
        int d = deg[i];
        invdeg[i] = 1.0f / (float)(d > 0 ? d : 1);
    }
    if (i == 0) offsets[N_NODES] = N_EDGES;   // sentinel
}

__global__ void scatter_kernel(const int* __restrict__ src, const int* __restrict__ dst,
                               const int* __restrict__ offsets, int* __restrict__ fill,
                               int* __restrict__ srcSorted) {
    int e = blockIdx.x * blockDim.x + threadIdx.x;
    if (e < N_EDGES) {
        int d_ = dst[e];
        int pos = offsets[d_] + atomicAdd(&fill[d_], 1);
        srcSorted[pos] = src[e];
    }
}

// ---------------- W hi/lo split into B-fragment layout (once per call) ----------------
__global__ void wsplit_kernel(const float* __restrict__ Wl, const float* __restrict__ Wr,
                              ushort* __restrict__ Whi, ushort* __restrict__ Wlo) {
    int t = blockIdx.x * blockDim.x + threadIdx.x;
    if (t >= N_LAYERS * 4 * 16 * 64) return;
    int lane  = t & 63;
    int ntile = (t >> 6) & 15;
    int s     = (t >> 10) & 3;
    int layer = t >> 12;
    int n = ntile * 16 + (lane & 15);
    int kbase = s * 32 + (lane >> 4) * 8;
    const float* W = (n < 128) ? (Wl + (size_t)layer * D * D + n)
                               : (Wr + (size_t)layer * D * D + (n - 128));
    size_t off = (size_t)t * 8;
#pragma unroll
    for (int j = 0; j < 8; ++j) {
        float w = W[(size_t)(kbase + j) * D];
        ushort hh = f2bf(w);
        Whi[off + j] = hh;
        Wlo[off + j] = f2bf(w - bf2f(hh));
    }
}

// ---------------- layer 0: h = x@Wl (bf16 col-pair packed), z = x@Wr + b (fp32) --------
__global__ __launch_bounds__(256) void gemm_hz(
        const float* __restrict__ X, const ushort* __restrict__ Whi,
        const ushort* __restrict__ Wlo, const float* __restrict__ bias,
        uint* __restrict__ h2out, float* __restrict__ z) {
    __shared__ ushort Ahi[2][4 * 64 * 8];
    __shared__ ushort Alo[2][4 * 64 * 8];

    int tid  = threadIdx.x;
    int lane = tid & 63;
    int wave = tid >> 6;

    int r    = tid >> 4;
    int t0   = tid & 15;
    int s_st = t0 >> 2;
    int q_st = t0 & 3;
    int lanep = (q_st << 4) | r;
    int stIdx = (s_st * 64 + (lanep ^ (s_st << 2))) * 8;

    int q  = lane >> 4;
    int cc = lane & 15;

    int ntileMap[4];
#pragma unroll
    for (int nt = 0; nt < 4; ++nt)
        ntileMap[nt] = (wave < 2) ? (wave * 2 + (nt & 1) + ((nt >> 1) << 2))
                                  : (wave * 4 + nt);

    float bsc[4] = {0.f, 0.f, 0.f, 0.f};
    if (wave >= 2) {
#pragma unroll
        for (int nt = 0; nt < 4; ++nt)
            bsc[nt] = bias[((wave * 4 + nt) - 8) * 16 + cc];
    }

    int row0 = blockIdx.x * 32;
#pragma unroll
    for (int st = 0; st < 2; ++st) {
        const float* xp = X + (size_t)(row0 + st * 16 + r) * D + t0 * 8;
        float4 v0 = *(const float4*)xp;
        float4 v1 = *(const float4*)(xp + 4);
        float a[8] = {v0.x, v0.y, v0.z, v0.w, v1.x, v1.y, v1.z, v1.w};
        ushort hi8[8], lo8[8];
#pragma unroll
        for (int j = 0; j < 8; ++j) {
            ushort hh = f2bf(a[j]);
            hi8[j] = hh;
            lo8[j] = f2bf(a[j] - bf2f(hh));
        }
        *(bf16x8*)&Ahi[st][stIdx] = *(bf16x8*)hi8;
        *(bf16x8*)&Alo[st][stIdx] = *(bf16x8*)lo8;
    }
    __syncthreads();

    floatx4 acc0[4], acc1[4];
#pragma unroll
    for (int nt = 0; nt < 4; ++nt) {
        acc0[nt] = (floatx4){0.f, 0.f, 0.f, 0.f};
        acc1[nt] = (floatx4){0.f, 0.f, 0.f, 0.f};
    }
#pragma unroll
    for (int s = 0; s < 4; ++s) {
        int aIdx = (s * 64 + (lane ^ (s << 2))) * 8;
        bf16x8 ah0 = *(const bf16x8*)&Ahi[0][aIdx];
        bf16x8 al0 = *(const bf16x8*)&Alo[0][aIdx];
        bf16x8 ah1 = *(const bf16x8*)&Ahi[1][aIdx];
        bf16x8 al1 = *(const bf16x8*)&Alo[1][aIdx];
#pragma unroll
        for (int nt = 0; nt < 4; ++nt) {
            size_t wo = ((size_t)(s * 16 + ntileMap[nt]) * 64 + lane) * 8;
            bf16x8 wh = *(const bf16x8*)&Whi[wo];
            bf16x8 wl = *(const bf16x8*)&Wlo[wo];
            acc0[nt] = __builtin_amdgcn_mfma_f32_16x16x32_bf16(ah0, wh, acc0[nt], 0, 0, 0);
            acc0[nt] = __builtin_amdgcn_mfma_f32_16x16x32_bf16(al0, wh, acc0[nt], 0, 0, 0);
            acc0[nt] = __builtin_amdgcn_mfma_f32_16x16x32_bf16(ah0, wl, acc0[nt], 0, 0, 0);
            acc1[nt] = __builtin_amdgcn_mfma_f32_16x16x32_bf16(ah1, wh, acc1[nt], 0, 0, 0);
            acc1[nt] = __builtin_amdgcn_mfma_f32_16x16x32_bf16(al1, wh, acc1[nt], 0, 0, 0);
            acc1[nt] = __builtin_amdgcn_mfma_f32_16x16x32_bf16(ah1, wl, acc1[nt], 0, 0, 0);
        }
    }

#pragma unroll
    for (int st = 0; st < 2; ++st) {
        floatx4* acc = st ? acc1 : acc0;
        int rowb = row0 + st * 16;
        if (wave < 2) {
#pragma unroll
            for (int p = 0; p < 2; ++p) {
                int c = wave * 32 + p * 16 + cc;
#pragma unroll
                for (int rr = 0; rr < 4; ++rr) {
                    uint lo = f2bf(acc[p][rr]);
                    uint hi = f2bf(acc[p + 2][rr]);
                    h2out[(size_t)(rowb + q * 4 + rr) * 64 + c] = lo | (hi << 16);
                }
            }
        } else {
#pragma unroll
            for (int nt = 0; nt < 4; ++nt) {
                int col = ((wave * 4 + nt) - 8) * 16 + cc;
#pragma unroll
                for (int rr = 0; rr < 4; ++rr) {
                    int row = rowb + q * 4 + rr;
                    z[(size_t)row * D + col] = acc[nt][rr] + bsc[nt];
                }
            }
        }
    }
}

// helper: write one activation value pair into A-fragment LDS (hi/lo split)
static __device__ __forceinline__ void frag_write(
        ushort* __restrict__ AhiSt, ushort* __restrict__ AloSt,
        int m, int c, float v) {
    int s_ = c >> 5, q_ = (c >> 3) & 3, j_ = c & 7;
    int elem = (s_ * 64 + (((q_ << 4) | m) ^ (s_ << 2))) * 8 + j_;
    ushort hh = f2bf(v);
    AhiSt[elem] = hh;
    AloSt[elem] = f2bf(v - bf2f(hh));
}

// ---------------- fused layer L: act = relu(mean_agg(h_{L-1}) + z_{L-1});
//                  h_L = act@Wl (packed), z_L = act@Wr + b (in-place over z) -------------
__global__ __launch_bounds__(256) void fused_layer(
        const uint* __restrict__ h2in, const int* __restrict__ srcSorted,
        const int* __restrict__ offsets, const float* __restrict__ invdeg,
        const float* __restrict__ zio, const ushort* __restrict__ Whi,
        const ushort* __restrict__ Wlo, const float* __restrict__ bias,
        uint* __restrict__ h2out) {
    __shared__ ushort Ahi[2][4 * 64 * 8];   // 8 KB
    __shared__ ushort Alo[2][4 * 64 * 8];   // 8 KB

    int tid  = threadIdx.x;
    int lane = tid & 63;
    int wave = tid >> 6;
    int row0 = blockIdx.x * 32;

    // ---- phase 1: aggregate 8 nodes/wave, pair-wise with hoisted loads ----
    int n0 = row0 + wave * 8;
    int offv = offsets[n0 + min(lane, 8)];          // lanes 0..8 hold offsets[n0..n0+8]
    int off0 = __shfl(offv, 0, 64);
    int total = __shfl(offv, 8, 64) - off0;
    int idxv = srcSorted[min(off0 + ((lane < total) ? lane : 0), N_EDGES - 1)];

#pragma unroll
    for (int p = 0; p < 4; ++p) {
        int i0 = 2 * p, i1 = i0 + 1;
        int s0 = __shfl(offv, i0, 64) - off0;
        int e0 = __shfl(offv, i1, 64) - off0;
        int e1 = __shfl(offv, i1 + 1, 64) - off0;
        int node0 = n0 + i0, node1 = n0 + i1;
        // z loads issued early (overlap with gather)
        float zx0 = zio[(size_t)node0 * D + lane];
        float zy0 = zio[(size_t)node0 * D + 64 + lane];
        float zx1 = zio[(size_t)node1 * D + lane];
        float zy1 = zio[(size_t)node1 * D + 64 + lane];
        float sx0 = 0.f, sy0 = 0.f, sx1 = 0.f, sy1 = 0.f;

        if (e1 <= 64) {
            // fast path: pair's combined span is inside idxv; chunks of 16 loads
            int d0 = min(s0, 63);
            for (int k = s0; k < e1; k += 16) {
                uint u[16];
#pragma unroll
                for (int j = 0; j < 16; ++j) {
                    int kk = k + j;
                    int sidx = __shfl(idxv, (kk < e1) ? kk : d0, 64);
                    u[j] = h2in[(size_t)sidx * 64 + lane];
                }
#pragma unroll
                for (int j = 0; j < 16; ++j) {
                    int kk = k + j;
                    float m = (kk < e1) ? 1.f : 0.f;
                    float vx = m * __uint_as_float(u[j] << 16);
                    float vy = m * __uint_as_float(u[j] & 0xffff0000u);
                    bool b0 = kk < e0;
                    sx0 += b0 ? vx : 0.f;
                    sy0 += b0 ? vy : 0.f;
                    sx1 += b0 ? 0.f : vx;
                    sy1 += b0 ? 0.f : vy;
                }
            }
        } else {
            // slow path: per-node fresh index loads (rare)
#pragma unroll
            for (int which = 0; which < 2; ++which) {
                int offn = off0 + (which ? e0 : s0);
                int cnt = which ? (e1 - e0) : (e0 - s0);
                float sx = 0.f, sy = 0.f;
                if (cnt > 0) {
                    int nv = cnt < 64 ? cnt : 64;
                    int idxn = srcSorted[offn + ((lane < nv) ? lane : 0)];
                    for (int k = 0; k < nv; k += 8) {
                        int sidx[8];
#pragma unroll
                        for (int j = 0; j < 8; ++j) {
                            int kk = k + j;
                            sidx[j] = __shfl(idxn, (kk < nv) ? kk : 0, 64);
                        }
                        uint u[8];
#pragma unroll
                        for (int j = 0; j < 8; ++j)
                            u[j] = h2in[(size_t)sidx[j] * 64 + lane];
#pragma unroll
                        for (int j = 0; j < 8; ++j) {
                            float m = ((k + j) < nv) ? 1.f : 0.f;
                            sx += m * __uint_as_float(u[j] << 16);
                            sy += m * __uint_as_float(u[j] & 0xffff0000u);
                        }
                    }
                    for (int k = 64; k < cnt; ++k) {
                        int s = srcSorted[offn + k];
                        uint u = h2in[(size_t)s * 64 + lane];
                        sx += __uint_as_float(u << 16);
                        sy += __uint_as_float(u & 0xffff0000u);
                    }
                }
                if (which) { sx1 = sx; sy1 = sy; }
                else       { sx0 = sx; sy0 = sy; }
            }
        }

        // epilogue of phase 1 for both nodes: mean + z + relu -> A-fragments
        {
            float inv = invdeg[node0];
            float ox = fmaxf(sx0 * inv + zx0, 0.f);
            float oy = fmaxf(sy0 * inv + zy0, 0.f);
            int local = wave * 8 + i0;
            int st = local >> 4, m = local & 15;
            frag_write(Ahi[st], Alo[st], m, lane, ox);
            frag_write(Ahi[st], Alo[st], m, lane + 64, oy);
        }
        {
            float inv = invdeg[node1];
            float ox = fmaxf(sx1 * inv + zx1, 0.f);
            float oy = fmaxf(sy1 * inv + zy1, 0.f);
            int local = wave * 8 + i1;
            int st = local >> 4, m = local & 15;
            frag_write(Ahi[st], Alo[st], m, lane, ox);
            frag_write(Ahi[st], Alo[st], m, lane + 64, oy);
        }
    }
    __syncthreads();

    // ---- phase 2: MFMA ----
    int q  = lane >> 4;
    int cc = lane & 15;
    int ntileMap[4];
#pragma unroll
    for (int nt = 0; nt < 4; ++nt)
        ntileMap[nt] = (wave < 2) ? (wave * 2 + (nt & 1) + ((nt >> 1) << 2))
                                  : (wave * 4 + nt);
    float bsc[4] = {0.f, 0.f, 0.f, 0.f};
    if (wave >= 2) {
#pragma unroll
        for (int nt = 0; nt < 4; ++nt)
            bsc[nt] = bias[((wave * 4 + nt) - 8) * 16 + cc];
    }

    floatx4 acc0[4], acc1[4];
#pragma unroll
    for (int nt = 0; nt < 4; ++nt) {
        acc0[nt] = (floatx4){0.f, 0.f, 0.f, 0.f};
        acc1[nt] = (floatx4){0.f, 0.f, 0.f, 0.f};
    }
#pragma unroll
    for (int s = 0; s < 4; ++s) {
        int aIdx = (s * 64 + (lane ^ (s << 2))) * 8;
        bf16x8 ah0 = *(const bf16x8*)&Ahi[0][aIdx];
        bf16x8 al0 = *(const bf16x8*)&Alo[0][aIdx];
        bf16x8 ah1 = *(const bf16x8*)&Ahi[1][aIdx];
        bf16x8 al1 = *(const bf16x8*)&Alo[1][aIdx];
#pragma unroll
        for (int nt = 0; nt < 4; ++nt) {
            size_t wo = ((size_t)(s * 16 + ntileMap[nt]) * 64 + lane) * 8;
            bf16x8 wh = *(const bf16x8*)&Whi[wo];
            bf16x8 wl = *(const bf16x8*)&Wlo[wo];
            acc0[nt] = __builtin_amdgcn_mfma_f32_16x16x32_bf16(ah0, wh, acc0[nt], 0, 0, 0);
            acc0[nt] = __builtin_amdgcn_mfma_f32_16x16x32_bf16(al0, wh, acc0[nt], 0, 0, 0);
            acc0[nt] = __builtin_amdgcn_mfma_f32_16x16x32_bf16(ah0, wl, acc0[nt], 0, 0, 0);
            acc1[nt] = __builtin_amdgcn_mfma_f32_16x16x32_bf16(ah1, wh, acc1[nt], 0, 0, 0);
            acc1[nt] = __builtin_amdgcn_mfma_f32_16x16x32_bf16(al1, wh, acc1[nt], 0, 0, 0);
            acc1[nt] = __builtin_amdgcn_mfma_f32_16x16x32_bf16(ah1, wl, acc1[nt], 0, 0, 0);
        }
    }

#pragma unroll
    for (int st = 0; st < 2; ++st) {
        floatx4* acc = st ? acc1 : acc0;
        int rowb = row0 + st * 16;
        if (wave < 2) {
#pragma unroll
            for (int p = 0; p < 2; ++p) {
                int c = wave * 32 + p * 16 + cc;
#pragma unroll
                for (int rr = 0; rr < 4; ++rr) {
                    uint lo = f2bf(acc[p][rr]);
                    uint hi = f2bf(acc[p + 2][rr]);
                    h2out[(size_t)(rowb + q * 4 + rr) * 64 + c] = lo | (hi << 16);
                }
            }
        } else {
#pragma unroll
            for (int nt = 0; nt < 4; ++nt) {
                int col = ((wave * 4 + nt) - 8) * 16 + cc;
#pragma unroll
                for (int rr = 0; rr < 4; ++rr) {
                    int row = rowb + q * 4 + rr;
                    ((float*)zio)[(size_t)row * D + col] = acc[nt][rr] + bsc[nt];
                }
            }
        }
    }
}

// ---------------- final: out = mean_agg(h9) + z9 (no relu) ----------------------------
__global__ __launch_bounds__(256) void agg_add_kernel(
        const uint* __restrict__ h2, const int* __restrict__ srcSorted,
        const int* __restrict__ offsets, const int* __restrict__ deg,
        const float* __restrict__ invdeg, const float* __restrict__ zin,
        float* __restrict__ out) {
    int node = blockIdx.x * 4 + (threadIdx.x >> 6);
    int lane = threadIdx.x & 63;
    int off = offsets[node];
    int cnt = deg[node];
    float sx = 0.f, sy = 0.f;
    if (cnt > 0) {
        int nv = cnt < 64 ? cnt : 64;
        int idxv = srcSorted[off + ((lane < nv) ? lane : 0)];
        for (int k = 0; k < nv; k += 8) {
            int sidx[8];
#pragma unroll
            for (int j = 0; j < 8; ++j) {
                int kk = k + j;
                sidx[j] = __shfl(idxv, (kk < nv) ? kk : 0, 64);
            }
            uint u[8];
#pragma unroll
            for (int j = 0; j < 8; ++j)
                u[j] = h2[(size_t)sidx[j] * 64 + lane];
#pragma unroll
            for (int j = 0; j < 8; ++j) {
                float m = ((k + j) < nv) ? 1.f : 0.f;
                sx += m * __uint_as_float(u[j] << 16);
                sy += m * __uint_as_float(u[j] & 0xffff0000u);
            }
        }
        for (int k = 64; k < cnt; ++k) {
            int s = srcSorted[off + k];
            uint u = h2[(size_t)s * 64 + lane];
            sx += __uint_as_float(u << 16);
            sy += __uint_as_float(u & 0xffff0000u);
        }
    }
    float inv = invdeg[node];
    out[(size_t)node * 128 + lane] = sx * inv + zin[(size_t)node * 128 + lane];
    out[(size_t)node * 128 + 64 + lane] = sy * inv + zin[(size_t)node * 128 + 64 + lane];
}

extern "C" void kernel_launch(void* const* d_in, const int* in_sizes, int n_in,
                              void* d_out, int out_size, void* d_ws, size_t ws_size,
                              hipStream_t stream) {
    const float* x  = (const float*)d_in[0];
    const float* Wl = (const float*)d_in[1];
    const float* Wr = (const float*)d_in[2];
    const float* b  = (const float*)d_in[3];
    const int*   ei = (const int*)d_in[4];
    const int* src = ei;
    const int* dst = ei + N_EDGES;
    float* out = (float*)d_out;

    char* w = (char*)d_ws;
    auto alloc = [&](size_t bytes) -> char* {
        char* p = w;
        w += (bytes + 255) & ~(size_t)255;
        return p;
    };
    float*  zx        = (float*)alloc((size_t)N_NODES * D * 4);
    uint*   hbufA     = (uint*)alloc((size_t)N_NODES * 64 * 4);
    uint*   hbufB     = (uint*)alloc((size_t)N_NODES * 64 * 4);
    ushort* Whi       = (ushort*)alloc((size_t)N_LAYERS * 4 * 16 * 64 * 8 * 2);
    ushort* Wlo       = (ushort*)alloc((size_t)N_LAYERS * 4 * 16 * 64 * 8 * 2);
    int*    deg       = (int*)alloc((size_t)N_NODES * 4);
    int*    offsets   = (int*)alloc((size_t)(N_NODES + 1) * 4);
    int*    fill      = (int*)alloc((size_t)N_NODES * 4);
    int*    srcSorted = (int*)alloc((size_t)N_EDGES * 4);
    int*    blockSums = (int*)alloc(128 * 4);
    int*    blockOffs = (int*)alloc(128 * 4);
    float*  invdeg    = (float*)alloc((size_t)N_NODES * 4);

    hipMemsetAsync(deg, 0, (size_t)N_NODES * 4, stream);
    hipMemsetAsync(fill, 0, (size_t)N_NODES * 4, stream);

    hist_kernel<<<(N_EDGES + 255) / 256, 256, 0, stream>>>(dst, deg);
    scanA_kernel<<<SCAN_BLOCKS, 1024, 0, stream>>>(deg, offsets, blockSums);
    scanB_kernel<<<1, 128, 0, stream>>>(blockSums, blockOffs);
    scanC_kernel<<<SCAN_BLOCKS, 1024, 0, stream>>>(offsets, blockOffs);
    invdeg_kernel<<<(N_NODES + 255) / 256, 256, 0, stream>>>(deg, invdeg, offsets);
    scatter_kernel<<<(N_EDGES + 255) / 256, 256, 0, stream>>>(src, dst, offsets, fill, srcSorted);
    wsplit_kernel<<<(N_LAYERS * 4 * 16 * 64 + 255) / 256, 256, 0, stream>>>(Wl, Wr, Whi, Wlo);

    // layer 0
    gemm_hz<<<N_NODES / 32, 256, 0, stream>>>(x, Whi, Wlo, b, hbufA, zx);
    // layers 1..9 fused
    uint* hin = hbufA;
    uint* hout = hbufB;
    for (int L = 1; L < N_LAYERS; ++L) {
        size_t woff = (size_t)L * 4 * 16 * 64 * 8;
        fused_layer<<<N_NODES / 32, 256, 0, stream>>>(
            hin, srcSorted, offsets, invdeg, zx,
            Whi + woff, Wlo + woff, b + (size_t)L * D, hout);
        uint* t = hin; hin = hout; hout = t;
    }
    // final aggregation (h9 is in `hin` after the swap)
    agg_add_kernel<<<N_NODES / 4, 256, 0, stream>>>(
        hin, srcSorted, offsets, deg, invdeg, zx, out);
}